// Round 10
// baseline (136.266 us; speedup 1.0000x reference)
//
#include <hip/hip_runtime.h>
#include <hip/hip_bf16.h>

// ---- problem constants ----
#define B_IMG   128
#define CH      3
#define HW      224
#define NPATCH  196          // tokens per image
#define TOKENS  25088        // B_IMG * NPATCH
#define PATCH   16
#define FDIM    768          // C*P*P (K of the GEMM)
#define DDIM    768          // output embed dim (N of the GEMM)
#define OUT_TOKENS ((size_t)TOKENS * DDIM)     // positions follow in d_out

#define WCONV_BLOCKS 576     // 768*768/4/256
#define POS_BLOCKS   98      // 25088/256

typedef short short8 __attribute__((ext_vector_type(8)));
typedef float f32x4  __attribute__((ext_vector_type(4)));

static __device__ __forceinline__ unsigned short f2bf(float v) {
  unsigned u = __float_as_uint(v);
  unsigned r = u + 0x7fffu + ((u >> 16) & 1u);
  return (unsigned short)(r >> 16);
}

static __device__ __forceinline__ void gload16(const short* g, short* l) {
  __builtin_amdgcn_global_load_lds(
      (const __attribute__((address_space(1))) void*)g,
      (__attribute__((address_space(3))) void*)l,
      16, 0, 0);
}

// ---- kernel 1: W -> bf16, and positions ----
__global__ __launch_bounds__(256) void prep2_kernel(
    const float* __restrict__ W, const int* __restrict__ ys,
    const int* __restrict__ xs, short* __restrict__ Wbf,
    float* __restrict__ pos) {
  const int blk = blockIdx.x;
  if (blk < WCONV_BLOCKS) {
    int i = (blk * 256 + threadIdx.x) * 4;
    float4 v = *(const float4*)&W[i];
    ushort4 o;
    o.x = f2bf(v.x); o.y = f2bf(v.y); o.z = f2bf(v.z); o.w = f2bf(v.w);
    *(ushort4*)&Wbf[i] = o;
  } else {
    int t = (blk - WCONV_BLOCKS) * 256 + threadIdx.x;   // 0..25087 exact
    pos[2 * t]     = (float)ys[t];
    pos[2 * t + 1] = (float)xs[t];
  }
}

// ---- kernel 2: FUSED gather + 128x128 BK=64 swizzled MFMA GEMM ----
// A gathered from x per K-step with COALESCED lanes (R7's failure was
// scattered 4B loads; here instr (i,h) = 4 token-rows x 16 consecutive px ->
// ~6 segments/instr, ~10.7M total requests ~= 2x the prep pass's measured-OK
// rate). cvt_pk f32->bf16 in-reg, ds_write_b16 into EXACTLY R9's swizzled
// LDS image: logical (row,k) at byte row*128 + ((k>>3)^(row&7))*16 + (k&7)*2.
// B staging, compute (rd0/rd1), epilogue, XCD swizzle: R9 verbatim (R9
// measured 0 bank conflicts with this image).
__global__ __launch_bounds__(256) void fused_kernel(
    const float* __restrict__ x, const int* __restrict__ ys,
    const int* __restrict__ xs, const short* __restrict__ Bw,
    const float* __restrict__ bias, float* __restrict__ C) {
  __shared__ short As[2][128 * 64];   // 16KB each
  __shared__ short Bs[2][128 * 64];   // total 64KB -> 2 blocks/CU

  const int tid  = threadIdx.x;
  const int w    = tid >> 6;
  const int l    = tid & 63;
  const int wrow = w >> 1;
  const int wcol = w & 1;
  const int lr   = l & 15;
  const int lg   = l >> 4;

  // bijective XCD swizzle: 1176 = 8*147 (R2: FETCH 118->34.6 MB); 6-runs of
  // consecutive nid share mt -> the 6 re-reads of an A-row are near-simultaneous
  // on one XCD -> L2-hit.
  const int id  = blockIdx.x;
  const int nid = (id & 7) * 147 + (id >> 3);
  const int m0  = (nid / 6) * 128;
  const int n0  = (nid % 6) * 128;

  // bias pinned complete before staging
  float bs4[4];
#pragma unroll
  for (int ni = 0; ni < 4; ++ni)
    bs4[ni] = bias[n0 + wcol * 64 + ni * 16 + lr];
#pragma unroll
  for (int ni = 0; ni < 4; ++ni) asm volatile("" : "+v"(bs4[ni]));

  f32x4 acc[4][4];
  const f32x4 z = {0.f, 0.f, 0.f, 0.f};
#pragma unroll
  for (int mi = 0; mi < 4; ++mi)
#pragma unroll
    for (int ni = 0; ni < 4; ++ni) acc[mi][ni] = z;

  // ---- A-gather lane geometry ----
  // instr (i 0..7, h 0..3): row = w*32 + i*4 + (l>>4), k = h*16 + (l&15).
  // K-step kt: channel c = kt>>2, patch-row base py0 = (kt&3)*4; element =
  // x[b*150528 + c*50176 + (y+py0+h)*224 + xc + (l&15)].
  const int l4  = l >> 4;
  const int l15 = l & 15;
  unsigned rbx[8];   // per-row gather base (y,xc,b folded; +l15)
  unsigned wad[8];   // LDS write base: row*128 + (l&7)*2  (bytes)
#pragma unroll
  for (int i = 0; i < 8; ++i) {
    const int row = w * 32 + i * 4 + l4;
    const int tok = m0 + row;
    const int b   = tok / NPATCH;
    rbx[i] = (unsigned)(b * (CH * HW * HW) + ys[tok] * HW + xs[tok] + l15);
    wad[i] = (unsigned)(row * 128 + (l & 7) * 2);
  }
  const unsigned b316 = (unsigned)(((l >> 3) & 1) << 4);

  // ---- B staging (R9 verbatim): pre-swizzled source col, linear LDS dest
  const int srow = l >> 3;
  const int scol = ((l & 7) ^ srow) * 8;
  const short* gB = Bw + (size_t)(n0 + w * 32 + srow) * FDIM + scol;

  float av[32];   // in-flight A f32 (static indexing only)

#define AISSUE(KT)                                                          \
  do {                                                                      \
    const float* xk_ = x + ((KT) >> 2) * (HW * HW) + (((KT) & 3) * 4) * HW; \
    _Pragma("unroll")                                                       \
    for (int i_ = 0; i_ < 8; ++i_)                                          \
      _Pragma("unroll")                                                     \
      for (int h_ = 0; h_ < 4; ++h_)                                        \
        av[i_ * 4 + h_] = xk_[rbx[i_] + h_ * HW];                           \
  } while (0)

#define BSTAGE(BUF, KT)                                                     \
  do {                                                                      \
    const int ko_ = (KT) * 64;                                              \
    _Pragma("unroll")                                                       \
    for (int c_ = 0; c_ < 4; ++c_)                                          \
      gload16(gB + (size_t)(c_ * 8) * FDIM + ko_,                           \
              &Bs[(BUF)][(w * 32 + c_ * 8) * 64]);                          \
  } while (0)

  // write addr = wad[i] + (((h*2+b3)<<4) ^ ((row&7)<<4)); (row&7)<<4 is
  // recoverable from wad: (wad>>3)&112. XOR distributes over <<4.
#define AWRITE(BUF)                                                         \
  do {                                                                      \
    char* ab_ = (char*)&As[(BUF)][0];                                       \
    _Pragma("unroll")                                                       \
    for (int i_ = 0; i_ < 8; ++i_) {                                        \
      const unsigned s716_ = (wad[i_] >> 3) & 112u;                         \
      _Pragma("unroll")                                                     \
      for (int h_ = 0; h_ < 4; ++h_) {                                      \
        unsigned pk_;                                                       \
        asm("v_cvt_pk_bf16_f32 %0, %1, %1" : "=v"(pk_)                      \
            : "v"(av[i_ * 4 + h_]));                                        \
        *(short*)(ab_ + (wad[i_] +                                          \
                         ((((unsigned)h_ << 5) | b316) ^ s716_))) =         \
            (short)pk_;                                                     \
      }                                                                     \
    }                                                                       \
  } while (0)

  // ---- swizzled fragment read (R9 verbatim): slot k8 at (k8^(row&7))*8
  const int rx  = lr & 7;
  const int rd0 = ((0 + lg) ^ rx) * 8;
  const int rd1 = ((4 + lg) ^ rx) * 8;

#define COMPUTE(BUF)                                                        \
  do {                                                                      \
    const short* Ab_ = As[(BUF)];                                           \
    const short* Bb_ = Bs[(BUF)];                                           \
    short8 a0_[4], b0_[4], a1_[4], b1_[4];                                  \
    _Pragma("unroll")                                                       \
    for (int mi = 0; mi < 4; ++mi) {                                        \
      const int r_ = (wrow * 64 + mi * 16 + lr) * 64;                       \
      a0_[mi] = *(const short8*)&Ab_[r_ + rd0];                             \
      a1_[mi] = *(const short8*)&Ab_[r_ + rd1];                             \
    }                                                                       \
    _Pragma("unroll")                                                       \
    for (int ni = 0; ni < 4; ++ni) {                                        \
      const int r_ = (wcol * 64 + ni * 16 + lr) * 64;                       \
      b0_[ni] = *(const short8*)&Bb_[r_ + rd0];                             \
      b1_[ni] = *(const short8*)&Bb_[r_ + rd1];                             \
    }                                                                       \
    __builtin_amdgcn_s_setprio(1);                                          \
    _Pragma("unroll")                                                       \
    for (int mi = 0; mi < 4; ++mi)                                          \
      _Pragma("unroll")                                                     \
      for (int ni = 0; ni < 4; ++ni) {                                      \
        acc[mi][ni] = __builtin_amdgcn_mfma_f32_16x16x32_bf16(              \
            a0_[mi], b0_[ni], acc[mi][ni], 0, 0, 0);                        \
        acc[mi][ni] = __builtin_amdgcn_mfma_f32_16x16x32_bf16(              \
            a1_[mi], b1_[ni], acc[mi][ni], 0, 0, 0);                        \
      }                                                                     \
    __builtin_amdgcn_s_setprio(0);                                          \
  } while (0)

  // ---- prologue: tile 0 ----
  AISSUE(0);
  BSTAGE(0, 0);
  asm volatile("s_waitcnt vmcnt(0)" ::: "memory");
  AWRITE(0);
  asm volatile("s_waitcnt lgkmcnt(0)" ::: "memory");
  __builtin_amdgcn_s_barrier();

  // ---- 12 K-steps, dbuf, one barrier per step ----
#pragma unroll 1
  for (int s2 = 0; s2 < 10; s2 += 2) {
    AISSUE(s2 + 1);
    BSTAGE(1, s2 + 1);
    __builtin_amdgcn_sched_barrier(0);   // keep issue ahead of compute
    COMPUTE(0);
    asm volatile("s_waitcnt vmcnt(0)" ::: "memory");
    AWRITE(1);
    asm volatile("s_waitcnt lgkmcnt(0)" ::: "memory");
    __builtin_amdgcn_s_barrier();

    AISSUE(s2 + 2);
    BSTAGE(0, s2 + 2);
    __builtin_amdgcn_sched_barrier(0);
    COMPUTE(1);
    asm volatile("s_waitcnt vmcnt(0)" ::: "memory");
    AWRITE(0);
    asm volatile("s_waitcnt lgkmcnt(0)" ::: "memory");
    __builtin_amdgcn_s_barrier();
  }
  // s = 10: stage tile 11
  AISSUE(11);
  BSTAGE(1, 11);
  __builtin_amdgcn_sched_barrier(0);
  COMPUTE(0);
  asm volatile("s_waitcnt vmcnt(0)" ::: "memory");
  AWRITE(1);
  asm volatile("s_waitcnt lgkmcnt(0)" ::: "memory");
  __builtin_amdgcn_s_barrier();
  // s = 11
  COMPUTE(1);

  // ---- epilogue: C/D layout col = lane&15, row = (lane>>4)*4 + j ----
#pragma unroll
  for (int ni = 0; ni < 4; ++ni) {
    const int col = n0 + wcol * 64 + ni * 16 + lr;
#pragma unroll
    for (int mi = 0; mi < 4; ++mi) {
      const int row = m0 + wrow * 64 + mi * 16 + lg * 4;
      const f32x4 v = acc[mi][ni];
#pragma unroll
      for (int j = 0; j < 4; ++j)
        C[(size_t)(row + j) * DDIM + col] = v[j] + bs4[ni];
    }
  }
#undef AISSUE
#undef BSTAGE
#undef AWRITE
#undef COMPUTE
}

// ---- fallback (ws too small): naive fused f32, correct but slow ----
__global__ __launch_bounds__(256) void naive_kernel(
    const float* __restrict__ x, const int* __restrict__ ys,
    const int* __restrict__ xs, const float* __restrict__ W,
    const float* __restrict__ bias, float* __restrict__ out) {
  __shared__ float prow[FDIM];
  const int tok = blockIdx.x;
  const int t   = threadIdx.x;
  const int b   = tok / NPATCH;
  const int y   = ys[tok];
  const int xc  = xs[tok];
  for (int i = t; i < FDIM; i += 256) {
    int c = i >> 8, rem = i & 255, py = rem >> 4, px = rem & 15;
    prow[i] = x[((size_t)(b * CH + c) * HW + y + py) * HW + xc + px];
  }
  __syncthreads();
  for (int dd = 0; dd < 3; ++dd) {
    const int d = t + dd * 256;
    float s = bias[d];
    const float4* wr = (const float4*)&W[(size_t)d * FDIM];
    const float4* pr = (const float4*)prow;
    for (int f4 = 0; f4 < FDIM / 4; ++f4) {
      float4 wv = wr[f4];
      float4 pv = pr[f4];
      s += wv.x * pv.x + wv.y * pv.y + wv.z * pv.z + wv.w * pv.w;
    }
    out[(size_t)tok * DDIM + d] = s;
  }
  if (t == 0) {
    float* pos = out + OUT_TOKENS;
    pos[(size_t)tok * 2]     = (float)y;
    pos[(size_t)tok * 2 + 1] = (float)xc;
  }
}

extern "C" void kernel_launch(void* const* d_in, const int* in_sizes, int n_in,
                              void* d_out, int out_size, void* d_ws, size_t ws_size,
                              hipStream_t stream) {
  const float* x    = (const float*)d_in[0];
  const int*   ys   = (const int*)d_in[1];
  const int*   xs   = (const int*)d_in[2];
  const float* W    = (const float*)d_in[3];
  const float* bias = (const float*)d_in[4];
  float* out = (float*)d_out;
  float* pos = out + OUT_TOKENS;

  const size_t w_bytes = (size_t)DDIM * FDIM * 2;   // 1,179,648
  if (ws_size >= w_bytes) {
    short* Wbf = (short*)d_ws;
    prep2_kernel<<<WCONV_BLOCKS + POS_BLOCKS, 256, 0, stream>>>(
        W, ys, xs, Wbf, pos);
    fused_kernel<<<(TOKENS / 128) * (DDIM / 128), 256, 0, stream>>>(
        x, ys, xs, Wbf, bias, out);
  } else {
    naive_kernel<<<TOKENS, 256, 0, stream>>>(x, ys, xs, W, bias, out);
  }
}

// Round 11
// 94.860 us; speedup vs baseline: 1.4365x; 1.4365x over previous
//
#include <hip/hip_runtime.h>
#include <hip/hip_bf16.h>

// ---- problem constants ----
#define B_IMG   128
#define CH      3
#define HW      224
#define NPATCH  196          // tokens per image
#define TOKENS  25088        // B_IMG * NPATCH
#define PATCH   16
#define FDIM    768          // C*P*P (K of the GEMM)
#define DDIM    768          // output embed dim (N of the GEMM)
#define TOKELEMS ((size_t)TOKENS * FDIM)
#define OUT_TOKENS ((size_t)TOKENS * DDIM)     // positions follow in d_out

#define GATHER_BLOCKS (TOKENS * (FDIM / 4) / 256)   // 18816
#define WCONV_BLOCKS  ((DDIM * FDIM / 4) / 256)     // 576

typedef short short8 __attribute__((ext_vector_type(8)));
typedef float f32x4  __attribute__((ext_vector_type(4)));

static __device__ __forceinline__ unsigned short f2bf(float v) {
  unsigned u = __float_as_uint(v);
  unsigned r = u + 0x7fffu + ((u >> 16) & 1u);
  return (unsigned short)(r >> 16);
}

static __device__ __forceinline__ void gload16(const short* g, short* l) {
  __builtin_amdgcn_global_load_lds(
      (const __attribute__((address_space(1))) void*)g,
      (__attribute__((address_space(3))) void*)l,
      16, 0, 0);
}

// ---- kernel 1: gather patches -> bf16 [TOKENS][768] + positions, W -> bf16 ----
__global__ __launch_bounds__(256) void prep_kernel(
    const float* __restrict__ x, const int* __restrict__ ys,
    const int* __restrict__ xs, const float* __restrict__ W,
    short* __restrict__ patches, short* __restrict__ Wbf,
    float* __restrict__ pos) {
  const int blk = blockIdx.x;
  if (blk < GATHER_BLOCKS) {
    int e   = blk * 256 + threadIdx.x;      // quad index
    int tok = e / 192;
    int q   = e - tok * 192;
    int f   = q * 4;
    int b   = tok / NPATCH;
    int y   = ys[tok];
    int xc  = xs[tok];
    int c   = f >> 8;
    int rem = f & 255;
    int py  = rem >> 4;
    int px  = rem & 15;
    const float* src = x + ((size_t)(b * CH + c) * HW + (y + py)) * HW + xc + px;
    ushort4 o;
    o.x = f2bf(src[0]); o.y = f2bf(src[1]); o.z = f2bf(src[2]); o.w = f2bf(src[3]);
    *(ushort4*)&patches[(size_t)tok * FDIM + f] = o;
    if (q == 0) {
      pos[(size_t)tok * 2]     = (float)y;
      pos[(size_t)tok * 2 + 1] = (float)xc;
    }
  } else {
    int i = ((blk - GATHER_BLOCKS) * 256 + threadIdx.x) * 4;
    float4 v = *(const float4*)&W[i];
    ushort4 o;
    o.x = f2bf(v.x); o.y = f2bf(v.y); o.z = f2bf(v.z); o.w = f2bf(v.w);
    *(ushort4*)&Wbf[i] = o;
  }
}

// ---- kernel 2: BARRIER-FREE per-wave GEMM ----
// The invariant shared by every 68-77us variant (R1/R2/R3/R5/R6/R7/R9) was
// block-wide barrier lockstep. Here each WAVE owns an independent 64x64
// output job with PRIVATE LDS staging (ring-2, BK=32): coalesced gload16
// (fixes R4's 16-segment scatter), per-wave counted vmcnt(8), ZERO barriers.
// Overwrite safety is pure data-flow: buffer b's ds_reads feed step-s MFMAs
// (compiler-inserted lgkm wait) which retire before step s+1 issues the
// re-stage of b. Swizzle (rule #21, 4-slot): source col (l&3)^(srow&3),
// read slot lg^(row&3) — banks verified 2/lane-pair = free.
__global__ __launch_bounds__(256) void gemm_kernel(
    const short* __restrict__ A,    // patches bf16 [TOKENS][768]
    const short* __restrict__ Bw,   // Wbf bf16 [768][768]
    const float* __restrict__ bias,
    float* __restrict__ C) {
  __shared__ short L[4][2][2][64 * 32];   // [wave][ring][A/B][2048] = 64KB

  const int tid = threadIdx.x;
  const int w   = tid >> 6;
  const int l   = tid & 63;
  const int lr  = l & 15;
  const int lg  = l >> 4;

  // XCD swizzle (1176 = 8*147, bijective; R4 measured FETCH 33MB with this).
  // Block = 4 consecutive jobs = same A-panel (mt), 4 nt -> L2 A-reuse.
  const int id  = blockIdx.x;
  const int nid = (id & 7) * 147 + (id >> 3);
  const int job = nid * 4 + w;            // 0..4703
  const int mt  = job / 12;
  const int nt  = job - mt * 12;
  const int m0  = mt * 64;
  const int n0  = nt * 64;

  // bias pinned complete before staging (vmcnt ledger stays clean)
  float bs4[4];
#pragma unroll
  for (int ni = 0; ni < 4; ++ni) bs4[ni] = bias[n0 + ni * 16 + lr];
#pragma unroll
  for (int ni = 0; ni < 4; ++ni) asm volatile("" : "+v"(bs4[ni]));

  f32x4 acc[4][4];
  const f32x4 z = {0.f, 0.f, 0.f, 0.f};
#pragma unroll
  for (int mi = 0; mi < 4; ++mi)
#pragma unroll
    for (int ni = 0; ni < 4; ++ni) acc[mi][ni] = z;

  // staging: gload16 covers 16 rows x 64B; lane -> row l>>2, source col-short
  // pre-swizzled ((l&3)^(srow&3))*8 so linear LDS dest holds swizzled image.
  const int srow = l >> 2;
  const int scol = ((l & 3) ^ (srow & 3)) * 8;
  const short* gA = A  + (size_t)(m0 + srow) * FDIM + scol;
  const short* gB = Bw + (size_t)(n0 + srow) * FDIM + scol;
  short* const lA0 = &L[w][0][0][0];
  short* const lB0 = &L[w][0][1][0];
  short* const lA1 = &L[w][1][0][0];
  short* const lB1 = &L[w][1][1][0];

#define STAGE(R, KT)                                                       \
  do {                                                                     \
    const int ko_ = (KT) * 32;                                             \
    short* la_ = (R) ? lA1 : lA0;                                          \
    short* lb_ = (R) ? lB1 : lB0;                                          \
    _Pragma("unroll")                                                      \
    for (int c_ = 0; c_ < 4; ++c_) {                                       \
      gload16(gA + (size_t)(c_ * 16) * FDIM + ko_, la_ + c_ * 512);        \
      gload16(gB + (size_t)(c_ * 16) * FDIM + ko_, lb_ + c_ * 512);        \
    }                                                                      \
  } while (0)

  // swizzled fragment read: logical slot lg lives at (lg ^ (row&3))*8
  const int rdo = ((lg ^ (lr & 3)) * 8);

#define COMPUTE(R)                                                         \
  do {                                                                     \
    const short* la_ = (R) ? lA1 : lA0;                                    \
    const short* lb_ = (R) ? lB1 : lB0;                                    \
    short8 a_[4], b_[4];                                                   \
    _Pragma("unroll")                                                      \
    for (int mi = 0; mi < 4; ++mi)                                         \
      a_[mi] = *(const short8*)&la_[(mi * 16 + lr) * 32 + rdo];            \
    _Pragma("unroll")                                                      \
    for (int ni = 0; ni < 4; ++ni)                                         \
      b_[ni] = *(const short8*)&lb_[(ni * 16 + lr) * 32 + rdo];            \
    _Pragma("unroll")                                                      \
    for (int mi = 0; mi < 4; ++mi)                                         \
      _Pragma("unroll")                                                    \
      for (int ni = 0; ni < 4; ++ni)                                       \
        acc[mi][ni] = __builtin_amdgcn_mfma_f32_16x16x32_bf16(             \
            a_[mi], b_[ni], acc[mi][ni], 0, 0, 0);                         \
  } while (0)

  // prologue: tile 0 in flight (8 loads)
  STAGE(0, 0);

  // main loop: per wave, no barriers anywhere. Stage s+1 (16 outstanding),
  // vmcnt(8) = tile s landed (s+1 stays in flight across the whole compute),
  // ds_read + MFMA.
#pragma unroll 1
  for (int s = 0; s < 23; ++s) {
    STAGE((s + 1) & 1, s + 1);
    asm volatile("s_waitcnt vmcnt(8)" ::: "memory");
    COMPUTE(s & 1);
  }
  asm volatile("s_waitcnt vmcnt(0)" ::: "memory");
  COMPUTE(23 & 1);

  // epilogue: C/D layout col = lane&15, row = (lane>>4)*4 + j
#pragma unroll
  for (int ni = 0; ni < 4; ++ni) {
    const int col = n0 + ni * 16 + lr;
#pragma unroll
    for (int mi = 0; mi < 4; ++mi) {
      const int row = m0 + mi * 16 + lg * 4;
      const f32x4 v = acc[mi][ni];
#pragma unroll
      for (int j = 0; j < 4; ++j)
        C[(size_t)(row + j) * DDIM + col] = v[j] + bs4[ni];
    }
  }
#undef STAGE
#undef COMPUTE
}

// ---- fallback (ws too small): naive fused f32, correct but slow ----
__global__ __launch_bounds__(256) void naive_kernel(
    const float* __restrict__ x, const int* __restrict__ ys,
    const int* __restrict__ xs, const float* __restrict__ W,
    const float* __restrict__ bias, float* __restrict__ out) {
  __shared__ float prow[FDIM];
  const int tok = blockIdx.x;
  const int t   = threadIdx.x;
  const int b   = tok / NPATCH;
  const int y   = ys[tok];
  const int xc  = xs[tok];
  for (int i = t; i < FDIM; i += 256) {
    int c = i >> 8, rem = i & 255, py = rem >> 4, px = rem & 15;
    prow[i] = x[((size_t)(b * CH + c) * HW + y + py) * HW + xc + px];
  }
  __syncthreads();
  for (int dd = 0; dd < 3; ++dd) {
    const int d = t + dd * 256;
    float s = bias[d];
    const float4* wr = (const float4*)&W[(size_t)d * FDIM];
    const float4* pr = (const float4*)prow;
    for (int f4 = 0; f4 < FDIM / 4; ++f4) {
      float4 wv = wr[f4];
      float4 pv = pr[f4];
      s += wv.x * pv.x + wv.y * pv.y + wv.z * pv.z + wv.w * pv.w;
    }
    out[(size_t)tok * DDIM + d] = s;
  }
  if (t == 0) {
    float* pos = out + OUT_TOKENS;
    pos[(size_t)tok * 2]     = (float)y;
    pos[(size_t)tok * 2 + 1] = (float)xc;
  }
}

extern "C" void kernel_launch(void* const* d_in, const int* in_sizes, int n_in,
                              void* d_out, int out_size, void* d_ws, size_t ws_size,
                              hipStream_t stream) {
  const float* x    = (const float*)d_in[0];
  const int*   ys   = (const int*)d_in[1];
  const int*   xs   = (const int*)d_in[2];
  const float* W    = (const float*)d_in[3];
  const float* bias = (const float*)d_in[4];
  float* out = (float*)d_out;
  float* pos = out + OUT_TOKENS;

  const size_t w_bytes = (size_t)DDIM * FDIM * 2;
  const size_t p_bytes = TOKELEMS * 2;
  if (ws_size >= w_bytes + p_bytes) {
    short* Wbf     = (short*)d_ws;
    short* patches = (short*)d_ws + (size_t)DDIM * FDIM;
    prep_kernel<<<GATHER_BLOCKS + WCONV_BLOCKS, 256, 0, stream>>>(
        x, ys, xs, W, patches, Wbf, pos);
    gemm_kernel<<<1176, 256, 0, stream>>>(patches, Wbf, bias, out);
  } else {
    naive_kernel<<<TOKENS, 256, 0, stream>>>(x, ys, xs, W, bias, out);
  }
}

// Round 12
// 88.485 us; speedup vs baseline: 1.5400x; 1.0720x over previous
//
#include <hip/hip_runtime.h>
#include <hip/hip_bf16.h>

// ---- problem constants ----
#define B_IMG   128
#define CH      3
#define HW      224
#define NPATCH  196          // tokens per image
#define TOKENS  25088        // B_IMG * NPATCH
#define PATCH   16
#define FDIM    768          // C*P*P (K of the GEMM)
#define DDIM    768          // output embed dim (N of the GEMM)
#define TOKELEMS ((size_t)TOKENS * FDIM)
#define OUT_TOKENS ((size_t)TOKENS * DDIM)     // positions follow in d_out

// fragment-major prep: thread = (row, k8) with k8 = k>>3 in 0..95
#define PREP_GATHER_BLOCKS (TOKENS * 96 / 256)   // 9408
#define PREP_W_BLOCKS      (DDIM * 96 / 256)     // 288

typedef short short8 __attribute__((ext_vector_type(8)));
typedef float f32x4  __attribute__((ext_vector_type(4)));

static __device__ __forceinline__ unsigned short f2bf(float v) {
  unsigned u = __float_as_uint(v);
  unsigned r = u + 0x7fffu + ((u >> 16) & 1u);
  return (unsigned short)(r >> 16);
}

// ---- kernel 1: gather + W-convert into FRAGMENT-MAJOR bricks ----
// Brick layout: PF[(mt16*24 + kt32)*512 + lg*128 + lr*8 + e]  (shorts)
//   where row = mt16*16 + lr, k = kt32*32 + lg*8 + e.
// A wave's MFMA fragment (lane l = lr + lg*16) is then 64 lanes x contiguous
// 16B at brick_base + l*8 -> ONE coalesced 1KB load. This moves the
// scatter cost into prep (which is HBM-bound anyway) and lets the GEMM run
// with NO LDS and NO barriers.
__global__ __launch_bounds__(256) void prep_kernel(
    const float* __restrict__ x, const int* __restrict__ ys,
    const int* __restrict__ xs, const float* __restrict__ W,
    short* __restrict__ PF, short* __restrict__ WF,
    float* __restrict__ pos) {
  const int t = blockIdx.x * 256 + threadIdx.x;
  if (blockIdx.x < PREP_GATHER_BLOCKS) {
    const int tok = t / 96;
    const int k8  = t - tok * 96;
    const int b   = tok / NPATCH;
    const int y   = ys[tok];
    const int xc  = xs[tok];
    // k = k8*8: c = k8>>5, py = (k8&31)>>1, px0 = (k8&1)*8
    const int c   = k8 >> 5;
    const int rem = k8 & 31;
    const int py  = rem >> 1;
    const int px0 = (rem & 1) * 8;
    const float* src = x + (size_t)(b * CH + c) * (HW * HW) +
                       (size_t)(y + py) * HW + xc + px0;
    float4 v0 = *(const float4*)src;        // f32-aligned, 16B
    float4 v1 = *(const float4*)(src + 4);
    short8 o;
    o[0] = (short)f2bf(v0.x); o[1] = (short)f2bf(v0.y);
    o[2] = (short)f2bf(v0.z); o[3] = (short)f2bf(v0.w);
    o[4] = (short)f2bf(v1.x); o[5] = (short)f2bf(v1.y);
    o[6] = (short)f2bf(v1.z); o[7] = (short)f2bf(v1.w);
    const size_t addr = ((size_t)(tok >> 4) * 24 + (k8 >> 2)) * 512 +
                        (k8 & 3) * 128 + (tok & 15) * 8;
    *(short8*)&PF[addr] = o;
    if (k8 == 0) {
      pos[(size_t)tok * 2]     = (float)y;
      pos[(size_t)tok * 2 + 1] = (float)xc;
    }
  } else {
    const int t2 = t - PREP_GATHER_BLOCKS * 256;
    const int n  = t2 / 96;
    const int k8 = t2 - n * 96;
    const float* src = W + (size_t)n * FDIM + k8 * 8;
    float4 v0 = *(const float4*)src;
    float4 v1 = *(const float4*)(src + 4);
    short8 o;
    o[0] = (short)f2bf(v0.x); o[1] = (short)f2bf(v0.y);
    o[2] = (short)f2bf(v0.z); o[3] = (short)f2bf(v0.w);
    o[4] = (short)f2bf(v1.x); o[5] = (short)f2bf(v1.y);
    o[6] = (short)f2bf(v1.z); o[7] = (short)f2bf(v1.w);
    const size_t addr = ((size_t)(n >> 4) * 24 + (k8 >> 2)) * 512 +
                        (k8 & 3) * 128 + (n & 15) * 8;
    *(short8*)&WF[addr] = o;
  }
}

// ---- kernel 2: ZERO-LDS ZERO-BARRIER register GEMM on fragment-major ops ----
// Each wave owns a 64x64 output job. Per K-step: 8 coalesced 1KB
// global_load_dwordx4 (A 4 bricks + B 4 bricks) into the alternate register
// set, per-wave vmcnt(8), 16 MFMA. No LDS round-trip anywhere: the exact
// failure of R4 (16-segment scattered frag loads) is gone because bricks are
// fragment-major; the invariant cost of R1-R11 (LDS write port + ds_read +
// sync quanta) is gone because there is no staging.
__global__ __launch_bounds__(256) void gemm_kernel(
    const short* __restrict__ PF,   // fragment-major patches
    const short* __restrict__ WF,   // fragment-major W
    const float* __restrict__ bias,
    float* __restrict__ C) {
  const int tid = threadIdx.x;
  const int w   = tid >> 6;
  const int l   = tid & 63;
  const int lr  = l & 15;
  const int lg  = l >> 4;

  // XCD swizzle (1176 = 8*147, bijective; R4/R11 measured FETCH ~33MB).
  // 12 consecutive jobs share an A row-panel -> same-XCD L2 reuse.
  const int id  = blockIdx.x;
  const int nid = (id & 7) * 147 + (id >> 3);
  const int job = nid * 4 + w;            // 0..4703
  const int mt  = job / 12;               // 392 M-tiles of 64
  const int nt  = job - mt * 12;          // 12 N-tiles of 64
  const int m0  = mt * 64;
  const int n0  = nt * 64;

  // fragment base pointers: brick (mt16, kt) at ((mt16*24)+kt)*512 + l*8
  const short* pA = PF + (size_t)(m0 >> 4) * 24 * 512 + l * 8;
  const short* pB = WF + (size_t)(n0 >> 4) * 24 * 512 + l * 8;

  float bs4[4];
#pragma unroll
  for (int ni = 0; ni < 4; ++ni) bs4[ni] = bias[n0 + ni * 16 + lr];
#pragma unroll
  for (int ni = 0; ni < 4; ++ni) asm volatile("" : "+v"(bs4[ni]));

  f32x4 acc[4][4];
  const f32x4 z = {0.f, 0.f, 0.f, 0.f};
#pragma unroll
  for (int mi = 0; mi < 4; ++mi)
#pragma unroll
    for (int ni = 0; ni < 4; ++ni) acc[mi][ni] = z;

  short8 A0[4], B0[4], A1[4], B1[4];   // named sets, static indexing (rule #20)

#define LOADSET(Af, Bf, KT)                                                  \
  do {                                                                       \
    const size_t ko_ = (size_t)(KT) * 512;                                   \
    _Pragma("unroll")                                                        \
    for (int i = 0; i < 4; ++i)                                              \
      Af[i] = *(const short8*)(pA + (size_t)i * 12288 + ko_);                \
    _Pragma("unroll")                                                        \
    for (int i = 0; i < 4; ++i)                                              \
      Bf[i] = *(const short8*)(pB + (size_t)i * 12288 + ko_);                \
  } while (0)

#define MFMASET(Af, Bf)                                                      \
  do {                                                                       \
    __builtin_amdgcn_s_setprio(1);                                           \
    _Pragma("unroll")                                                        \
    for (int mi = 0; mi < 4; ++mi)                                           \
      _Pragma("unroll")                                                      \
      for (int ni = 0; ni < 4; ++ni)                                         \
        acc[mi][ni] = __builtin_amdgcn_mfma_f32_16x16x32_bf16(               \
            Af[mi], Bf[ni], acc[mi][ni], 0, 0, 0);                           \
    __builtin_amdgcn_s_setprio(0);                                           \
  } while (0)

  LOADSET(A0, B0, 0);
#pragma unroll 1
  for (int s = 0; s < 24; s += 2) {
    LOADSET(A1, B1, s + 1);                           // 16 outstanding
    asm volatile("s_waitcnt vmcnt(8)" ::: "memory");  // set-s landed
    MFMASET(A0, B0);
    const int k2 = (s + 2 < 24) ? s + 2 : 0;          // tail: harmless reload
    LOADSET(A0, B0, k2);
    asm volatile("s_waitcnt vmcnt(8)" ::: "memory");
    MFMASET(A1, B1);
  }

  // epilogue: C/D layout col = lane&15, row = (lane>>4)*4 + j
#pragma unroll
  for (int ni = 0; ni < 4; ++ni) {
    const int col = n0 + ni * 16 + lr;
#pragma unroll
    for (int mi = 0; mi < 4; ++mi) {
      const int row = m0 + mi * 16 + lg * 4;
      const f32x4 v = acc[mi][ni];
#pragma unroll
      for (int j = 0; j < 4; ++j)
        C[(size_t)(row + j) * DDIM + col] = v[j] + bs4[ni];
    }
  }
#undef LOADSET
#undef MFMASET
}

// ---- fallback (ws too small): naive fused f32, correct but slow ----
__global__ __launch_bounds__(256) void naive_kernel(
    const float* __restrict__ x, const int* __restrict__ ys,
    const int* __restrict__ xs, const float* __restrict__ W,
    const float* __restrict__ bias, float* __restrict__ out) {
  __shared__ float prow[FDIM];
  const int tok = blockIdx.x;
  const int t   = threadIdx.x;
  const int b   = tok / NPATCH;
  const int y   = ys[tok];
  const int xc  = xs[tok];
  for (int i = t; i < FDIM; i += 256) {
    int c = i >> 8, rem = i & 255, py = rem >> 4, px = rem & 15;
    prow[i] = x[((size_t)(b * CH + c) * HW + y + py) * HW + xc + px];
  }
  __syncthreads();
  for (int dd = 0; dd < 3; ++dd) {
    const int d = t + dd * 256;
    float s = bias[d];
    const float4* wr = (const float4*)&W[(size_t)d * FDIM];
    const float4* pr = (const float4*)prow;
    for (int f4 = 0; f4 < FDIM / 4; ++f4) {
      float4 wv = wr[f4];
      float4 pv = pr[f4];
      s += wv.x * pv.x + wv.y * pv.y + wv.z * pv.z + wv.w * pv.w;
    }
    out[(size_t)tok * DDIM + d] = s;
  }
  if (t == 0) {
    float* pos = out + OUT_TOKENS;
    pos[(size_t)tok * 2]     = (float)y;
    pos[(size_t)tok * 2 + 1] = (float)xc;
  }
}

extern "C" void kernel_launch(void* const* d_in, const int* in_sizes, int n_in,
                              void* d_out, int out_size, void* d_ws, size_t ws_size,
                              hipStream_t stream) {
  const float* x    = (const float*)d_in[0];
  const int*   ys   = (const int*)d_in[1];
  const int*   xs   = (const int*)d_in[2];
  const float* W    = (const float*)d_in[3];
  const float* bias = (const float*)d_in[4];
  float* out = (float*)d_out;
  float* pos = out + OUT_TOKENS;

  const size_t w_bytes = (size_t)DDIM * FDIM * 2;   // WF: 1,179,648
  const size_t p_bytes = TOKELEMS * 2;              // PF: 38,535,168
  if (ws_size >= w_bytes + p_bytes) {
    short* WF = (short*)d_ws;
    short* PF = (short*)d_ws + (size_t)DDIM * FDIM;
    prep_kernel<<<PREP_GATHER_BLOCKS + PREP_W_BLOCKS, 256, 0, stream>>>(
        x, ys, xs, W, PF, WF, pos);
    gemm_kernel<<<1176, 256, 0, stream>>>(PF, WF, bias, out);
  } else {
    naive_kernel<<<TOKENS, 256, 0, stream>>>(x, ys, xs, W, bias, out);
  }
}

// Round 13
// 75.663 us; speedup vs baseline: 1.8010x; 1.1695x over previous
//
#include <hip/hip_runtime.h>
#include <hip/hip_bf16.h>

// ---- problem constants ----
#define B_IMG   128
#define CH      3
#define HW      224
#define NPATCH  196          // tokens per image
#define TOKENS  25088        // B_IMG * NPATCH
#define PATCH   16
#define FDIM    768          // C*P*P (K of the GEMM)
#define DDIM    768          // output embed dim (N of the GEMM)
#define TOKELEMS ((size_t)TOKENS * FDIM)
#define OUT_TOKENS ((size_t)TOKENS * DDIM)     // positions follow in d_out

// brick = (tile16, kt32): 512 shorts = 1KB. Gather: 1568*24 = 37632 bricks;
// W: 48*24 = 1152 bricks. One WAVE per brick -> 1KB coalesced store.
#define GATHER_BRICK_BLOCKS (37632 / 4)   // 9408
#define W_BRICK_BLOCKS      (1152 / 4)    // 288

typedef short short8 __attribute__((ext_vector_type(8)));
typedef float f32x4  __attribute__((ext_vector_type(4)));

static __device__ __forceinline__ unsigned short f2bf(float v) {
  unsigned u = __float_as_uint(v);
  unsigned r = u + 0x7fffu + ((u >> 16) & 1u);
  return (unsigned short)(r >> 16);
}

// ---- kernel 1: gather + W-convert into FRAGMENT-MAJOR bricks ----
// Brick layout (shorts): PF[brick*512 + (lg*16+lr)*8 + e]
//   brick = tile16*24 + kt;  row = tile16*16 + lr;  k = kt*32 + lg*8 + e.
// R12 post-mortem: thread-per-(row,k8) prep scattered 16B writes at 256B
// stride -> write-allocate RMW, 54us. Here ONE WAVE builds ONE brick: lane
// l=(lr,lg) reads its 8 floats (32B contiguous; lg pairs of a token fuse
// into 64B row segments) and the wave's store is exactly 64x16B = 1KB
// contiguous. Reads match the proven-fine R1-prep scatter profile.
__global__ __launch_bounds__(256) void prep_kernel(
    const float* __restrict__ x, const int* __restrict__ ys,
    const int* __restrict__ xs, const float* __restrict__ W,
    short* __restrict__ PF, short* __restrict__ WF,
    float* __restrict__ pos) {
  const int w  = threadIdx.x >> 6;
  const int l  = threadIdx.x & 63;
  const int lr = l & 15;
  const int lg = l >> 4;
  const int k8rem = lg & 3;              // k8 = kt*4 + lg

  if (blockIdx.x < GATHER_BRICK_BLOCKS) {
    const int brick  = blockIdx.x * 4 + w;      // 0..37631
    const int tile16 = brick / 24;
    const int kt     = brick - tile16 * 24;
    const int tok    = tile16 * 16 + lr;
    const int b      = tok / NPATCH;
    const int y      = ys[tok];
    const int xc     = xs[tok];
    const int k8     = kt * 4 + k8rem;          // 0..95
    const int c      = k8 >> 5;
    const int rem    = k8 & 31;
    const int py     = rem >> 1;
    const int px0    = (rem & 1) * 8;
    const float* src = x + (size_t)(b * CH + c) * (HW * HW) +
                       (size_t)(y + py) * HW + xc + px0;
    float4 v0 = *(const float4*)src;
    float4 v1 = *(const float4*)(src + 4);
    short8 o;
    o[0] = (short)f2bf(v0.x); o[1] = (short)f2bf(v0.y);
    o[2] = (short)f2bf(v0.z); o[3] = (short)f2bf(v0.w);
    o[4] = (short)f2bf(v1.x); o[5] = (short)f2bf(v1.y);
    o[6] = (short)f2bf(v1.z); o[7] = (short)f2bf(v1.w);
    *(short8*)&PF[(size_t)brick * 512 + l * 8] = o;   // wave: 1KB contiguous
    if (kt == 0 && lg == 0) {
      pos[(size_t)tok * 2]     = (float)y;
      pos[(size_t)tok * 2 + 1] = (float)xc;
    }
  } else {
    const int brick  = (blockIdx.x - GATHER_BRICK_BLOCKS) * 4 + w;  // 0..1151
    const int tile16 = brick / 24;
    const int kt     = brick - tile16 * 24;
    const int n      = tile16 * 16 + lr;
    const int k8     = kt * 4 + k8rem;
    const float* src = W + (size_t)n * FDIM + k8 * 8;
    float4 v0 = *(const float4*)src;
    float4 v1 = *(const float4*)(src + 4);
    short8 o;
    o[0] = (short)f2bf(v0.x); o[1] = (short)f2bf(v0.y);
    o[2] = (short)f2bf(v0.z); o[3] = (short)f2bf(v0.w);
    o[4] = (short)f2bf(v1.x); o[5] = (short)f2bf(v1.y);
    o[6] = (short)f2bf(v1.z); o[7] = (short)f2bf(v1.w);
    *(short8*)&WF[(size_t)brick * 512 + l * 8] = o;
  }
}

// ---- kernel 2: ZERO-LDS ZERO-BARRIER register GEMM (R12 verbatim) ----
// Each wave owns a 64x64 job; per K-step 8 coalesced 1KB dwordx4 loads into
// the alternate register set, per-wave vmcnt(8), 16 MFMA. R12 measured this
// at ~33us (out of top-5).
__global__ __launch_bounds__(256) void gemm_kernel(
    const short* __restrict__ PF,   // fragment-major patches
    const short* __restrict__ WF,   // fragment-major W
    const float* __restrict__ bias,
    float* __restrict__ C) {
  const int tid = threadIdx.x;
  const int w   = tid >> 6;
  const int l   = tid & 63;
  const int lr  = l & 15;
  const int lg  = l >> 4;

  // XCD swizzle (1176 = 8*147, bijective): 12 consecutive jobs share an
  // A row-panel -> same-XCD L2 reuse (R4/R11/R12 measured FETCH ~33MB).
  const int id  = blockIdx.x;
  const int nid = (id & 7) * 147 + (id >> 3);
  const int job = nid * 4 + w;            // 0..4703
  const int mt  = job / 12;               // 392 M-tiles of 64
  const int nt  = job - mt * 12;          // 12 N-tiles of 64
  const int m0  = mt * 64;
  const int n0  = nt * 64;

  const short* pA = PF + (size_t)(m0 >> 4) * 24 * 512 + l * 8;
  const short* pB = WF + (size_t)(n0 >> 4) * 24 * 512 + l * 8;

  float bs4[4];
#pragma unroll
  for (int ni = 0; ni < 4; ++ni) bs4[ni] = bias[n0 + ni * 16 + lr];
#pragma unroll
  for (int ni = 0; ni < 4; ++ni) asm volatile("" : "+v"(bs4[ni]));

  f32x4 acc[4][4];
  const f32x4 z = {0.f, 0.f, 0.f, 0.f};
#pragma unroll
  for (int mi = 0; mi < 4; ++mi)
#pragma unroll
    for (int ni = 0; ni < 4; ++ni) acc[mi][ni] = z;

  short8 A0[4], B0[4], A1[4], B1[4];   // named sets, static indexing (rule #20)

#define LOADSET(Af, Bf, KT)                                                  \
  do {                                                                       \
    const size_t ko_ = (size_t)(KT) * 512;                                   \
    _Pragma("unroll")                                                        \
    for (int i = 0; i < 4; ++i)                                              \
      Af[i] = *(const short8*)(pA + (size_t)i * 12288 + ko_);                \
    _Pragma("unroll")                                                        \
    for (int i = 0; i < 4; ++i)                                              \
      Bf[i] = *(const short8*)(pB + (size_t)i * 12288 + ko_);                \
  } while (0)

#define MFMASET(Af, Bf)                                                      \
  do {                                                                       \
    __builtin_amdgcn_s_setprio(1);                                           \
    _Pragma("unroll")                                                        \
    for (int mi = 0; mi < 4; ++mi)                                           \
      _Pragma("unroll")                                                      \
      for (int ni = 0; ni < 4; ++ni)                                         \
        acc[mi][ni] = __builtin_amdgcn_mfma_f32_16x16x32_bf16(               \
            Af[mi], Bf[ni], acc[mi][ni], 0, 0, 0);                           \
    __builtin_amdgcn_s_setprio(0);                                           \
  } while (0)

  LOADSET(A0, B0, 0);
#pragma unroll 1
  for (int s = 0; s < 24; s += 2) {
    LOADSET(A1, B1, s + 1);                           // 16 outstanding
    asm volatile("s_waitcnt vmcnt(8)" ::: "memory");  // set-s landed
    MFMASET(A0, B0);
    const int k2 = (s + 2 < 24) ? s + 2 : 0;          // tail: harmless reload
    LOADSET(A0, B0, k2);
    asm volatile("s_waitcnt vmcnt(8)" ::: "memory");
    MFMASET(A1, B1);
  }

  // epilogue: C/D layout col = lane&15, row = (lane>>4)*4 + j
#pragma unroll
  for (int ni = 0; ni < 4; ++ni) {
    const int col = n0 + ni * 16 + lr;
#pragma unroll
    for (int mi = 0; mi < 4; ++mi) {
      const int row = m0 + mi * 16 + lg * 4;
      const f32x4 v = acc[mi][ni];
#pragma unroll
      for (int j = 0; j < 4; ++j)
        C[(size_t)(row + j) * DDIM + col] = v[j] + bs4[ni];
    }
  }
#undef LOADSET
#undef MFMASET
}

// ---- fallback (ws too small): naive fused f32, correct but slow ----
__global__ __launch_bounds__(256) void naive_kernel(
    const float* __restrict__ x, const int* __restrict__ ys,
    const int* __restrict__ xs, const float* __restrict__ W,
    const float* __restrict__ bias, float* __restrict__ out) {
  __shared__ float prow[FDIM];
  const int tok = blockIdx.x;
  const int t   = threadIdx.x;
  const int b   = tok / NPATCH;
  const int y   = ys[tok];
  const int xc  = xs[tok];
  for (int i = t; i < FDIM; i += 256) {
    int c = i >> 8, rem = i & 255, py = rem >> 4, px = rem & 15;
    prow[i] = x[((size_t)(b * CH + c) * HW + y + py) * HW + xc + px];
  }
  __syncthreads();
  for (int dd = 0; dd < 3; ++dd) {
    const int d = t + dd * 256;
    float s = bias[d];
    const float4* wr = (const float4*)&W[(size_t)d * FDIM];
    const float4* pr = (const float4*)prow;
    for (int f4 = 0; f4 < FDIM / 4; ++f4) {
      float4 wv = wr[f4];
      float4 pv = pr[f4];
      s += wv.x * pv.x + wv.y * pv.y + wv.z * pv.z + wv.w * pv.w;
    }
    out[(size_t)tok * DDIM + d] = s;
  }
  if (t == 0) {
    float* pos = out + OUT_TOKENS;
    pos[(size_t)tok * 2]     = (float)y;
    pos[(size_t)tok * 2 + 1] = (float)xc;
  }
}

extern "C" void kernel_launch(void* const* d_in, const int* in_sizes, int n_in,
                              void* d_out, int out_size, void* d_ws, size_t ws_size,
                              hipStream_t stream) {
  const float* x    = (const float*)d_in[0];
  const int*   ys   = (const int*)d_in[1];
  const int*   xs   = (const int*)d_in[2];
  const float* W    = (const float*)d_in[3];
  const float* bias = (const float*)d_in[4];
  float* out = (float*)d_out;
  float* pos = out + OUT_TOKENS;

  const size_t w_bytes = (size_t)DDIM * FDIM * 2;   // WF: 1,179,648
  const size_t p_bytes = TOKELEMS * 2;              // PF: 38,535,168
  if (ws_size >= w_bytes + p_bytes) {
    short* WF = (short*)d_ws;
    short* PF = (short*)d_ws + (size_t)DDIM * FDIM;
    prep_kernel<<<GATHER_BRICK_BLOCKS + W_BRICK_BLOCKS, 256, 0, stream>>>(
        x, ys, xs, W, PF, WF, pos);
    gemm_kernel<<<1176, 256, 0, stream>>>(PF, WF, bias, out);
  } else {
    naive_kernel<<<TOKENS, 256, 0, stream>>>(x, ys, xs, W, bias, out);
  }
}